// Round 1
// 3743.157 us; speedup vs baseline: 1.0884x; 1.0884x over previous
//
#include <hip/hip_runtime.h>
#include <hip/hip_bf16.h>
#include <math.h>

// ViT-Base forward: B=32, C=3, IMG=224, NP=14, PS=16, IN_DIM=768, D=768,
// NH=12, DH=64, L=12, MLP=3072, OUT=1000, S=197
#define VB   32
#define VD   768
#define VNH  12
#define VDH  64
#define VL   12
#define VMLP 3072
#define VOUT 1000
#define VS   197
#define VNPAT 196

typedef _Float16 half8 __attribute__((ext_vector_type(8)));
typedef _Float16 half4 __attribute__((ext_vector_type(4)));
typedef float f32x4 __attribute__((ext_vector_type(4)));

static __device__ __forceinline__ unsigned short f2h(float f) {
  _Float16 h = (_Float16)f;
  return __builtin_bit_cast(unsigned short, h);
}
static __device__ __forceinline__ float h2f(unsigned short u) {
  return (float)__builtin_bit_cast(_Float16, u);
}

// async global->LDS, 16B per lane; LDS dest = wave-uniform base + lane*16
static __device__ __forceinline__ void gload_lds16(const void* g, void* l) {
  __builtin_amdgcn_global_load_lds(
      (const __attribute__((address_space(1))) unsigned int*)g,
      (__attribute__((address_space(3))) unsigned int*)l, 16, 0, 0);
}

// ---------------------------------------------------------------- patchify
__global__ __launch_bounds__(256) void patchify_kernel(
    const float* __restrict__ x, unsigned short* __restrict__ P) {
  int bp = blockIdx.x;                 // b*196 + p
  int b = bp / VNPAT, p = bp - b * VNPAT;
  int py = p / 14, px = p - py * 14;
  int t = threadIdx.x;
  int iy = t >> 4, ix = t & 15;
#pragma unroll
  for (int c = 0; c < 3; c++) {
    float val = x[(((size_t)(b * 3 + c) * 224) + (py * 16 + iy)) * 224 + px * 16 + ix];
    P[(size_t)bp * 768 + c * 256 + t] = f2h(val);
  }
}

// ---------------------------------------------------------------- transpose
// W (fp32, K x N, layer-strided) -> WT (fp16, N x K)
__global__ __launch_bounds__(256) void transpose_kernel(
    const float* __restrict__ W, unsigned short* __restrict__ WT,
    int K, int N) {
  __shared__ float ts[64][65];
  int n0 = blockIdx.x * 64, k0 = blockIdx.y * 64;
  const float* Wl = W + (size_t)blockIdx.z * K * N;
  unsigned short* WTl = WT + (size_t)blockIdx.z * K * N;
  int t = threadIdx.x;
  int r = t >> 4, c4 = (t & 15) * 4;
#pragma unroll
  for (int p = 0; p < 4; ++p) {
    int row = p * 16 + r;
    float4 v = *(const float4*)(Wl + (size_t)(k0 + row) * N + n0 + c4);
    ts[row][c4 + 0] = v.x; ts[row][c4 + 1] = v.y;
    ts[row][c4 + 2] = v.z; ts[row][c4 + 3] = v.w;
  }
  __syncthreads();
#pragma unroll
  for (int p = 0; p < 4; ++p) {
    int n = p * 16 + r;
    ushort4 o;
    o.x = f2h(ts[c4 + 0][n]);
    o.y = f2h(ts[c4 + 1][n]);
    o.z = f2h(ts[c4 + 2][n]);
    o.w = f2h(ts[c4 + 3][n]);
    *(ushort4*)(WTl + (size_t)(n0 + n) * K + k0 + c4) = o;
  }
}

// ---------------------------------------------------------------- pack QKV
__global__ __launch_bounds__(256) void pack_qkv_kernel(
    const float* __restrict__ Wq, const float* __restrict__ Wk,
    const float* __restrict__ Wv, unsigned short* __restrict__ Wp) {
  size_t idx = (size_t)blockIdx.x * 256 + threadIdx.x;  // < 12*12*192*64
  int d = idx & 63;
  size_t r = idx >> 6;            // lh*192 + n
  int n = (int)(r % 192);
  size_t lh = r / 192;            // l*12 + h
  int which = n >> 6, e = n & 63;
  const float* W = which == 0 ? Wq : which == 1 ? Wk : Wv;
  Wp[idx] = f2h(W[(lh * 64 + e) * 64 + d]);
}

// ---------------------------------------------------------------- cls + pos
__global__ __launch_bounds__(256) void addpos_kernel(
    const float* __restrict__ cls, const float* __restrict__ pos,
    float* __restrict__ out) {
  int bs = blockIdx.x;                 // b*197 + s
  int s = bs % VS;
  int t = threadIdx.x;
  size_t o = (size_t)bs * VD;
#pragma unroll
  for (int j = 0; j < 3; j++) {
    int d = j * 256 + t;
    if (s == 0) out[o + d] = cls[d] + pos[d];
    else        out[o + d] += pos[(size_t)s * VD + d];
  }
}

// ---------------------------------------------------------------- layernorm
// fp32 in -> fp16 out
__global__ __launch_bounds__(256) void ln_kernel(
    const float* __restrict__ x, unsigned short* __restrict__ y,
    const float* __restrict__ g, const float* __restrict__ b) {
  int row = blockIdx.x;
  int t = threadIdx.x;
  const float* xr = x + (size_t)row * VD;
  float v0 = xr[t], v1 = xr[t + 256], v2 = xr[t + 512];
  float s = v0 + v1 + v2;
  float ss = v0 * v0 + v1 * v1 + v2 * v2;
#pragma unroll
  for (int off = 32; off; off >>= 1) {
    s  += __shfl_down(s, off);
    ss += __shfl_down(ss, off);
  }
  __shared__ float red[10];
  int wid = t >> 6, lane = t & 63;
  if (lane == 0) { red[wid] = s; red[4 + wid] = ss; }
  __syncthreads();
  if (t == 0) {
    float S  = red[0] + red[1] + red[2] + red[3];
    float SS = red[4] + red[5] + red[6] + red[7];
    float mu = S * (1.0f / VD);
    float var = SS * (1.0f / VD) - mu * mu;
    red[8] = mu;
    red[9] = rsqrtf(var + 1e-5f);
  }
  __syncthreads();
  float mu = red[8], rs = red[9];
  unsigned short* yr = y + (size_t)row * VD;
  yr[t]       = f2h((v0 - mu) * rs * g[t]       + b[t]);
  yr[t + 256] = f2h((v1 - mu) * rs * g[t + 256] + b[t + 256]);
  yr[t + 512] = f2h((v2 - mu) * rs * g[t + 512] + b[t + 512]);
}

// ---------------------------------------------------------------- QKV GEMM
// per head h: C[6304, 192] = xn[:, h*64:(h+1)*64] @ Wp[h]^T (+bias)
// out: qh/kh fp16 [bh][s][64]; vt fp16 [bh][d][208] (transposed)
__global__ __launch_bounds__(256) void qkv_gemm(
    const unsigned short* __restrict__ xn,     // [6304, 768] fp16
    const unsigned short* __restrict__ Wp,     // [12][192][64] fp16 (layer base)
    const float* __restrict__ bq, const float* __restrict__ bk,
    const float* __restrict__ bv,              // [12][64] each (layer base)
    unsigned short* __restrict__ qh, unsigned short* __restrict__ kh,
    unsigned short* __restrict__ vt) {
  __shared__ unsigned short As[128 * 72];
  __shared__ unsigned short Bs[192 * 72];
  int h = blockIdx.y;
  int bm = blockIdx.x * 128;
  int t = threadIdx.x;
  int srow = t >> 3;          // 0..31
  int scol = (t & 7) * 8;     // 0..56
#pragma unroll
  for (int p = 0; p < 4; ++p) {
    int row = p * 32 + srow;
    int grow = bm + row;
    uint4 val = make_uint4(0u, 0u, 0u, 0u);
    if (grow < VB * VS)
      val = *(const uint4*)(xn + (size_t)grow * VD + h * 64 + scol);
    *(uint4*)(&As[row * 72 + scol]) = val;
  }
#pragma unroll
  for (int p = 0; p < 6; ++p) {
    int row = p * 32 + srow;
    uint4 val = *(const uint4*)(Wp + ((size_t)h * 192 + row) * 64 + scol);
    *(uint4*)(&Bs[row * 72 + scol]) = val;
  }
  __syncthreads();
  int lane = t & 63, wv = t >> 6;
  int wm = (wv & 1) * 64, wn = (wv >> 1) * 96;
  int l15 = lane & 15, l4 = lane >> 4;
  f32x4 acc[4][6] = {};
#pragma unroll
  for (int kk = 0; kk < 64; kk += 32) {
    half8 af[4], bf[6];
#pragma unroll
    for (int i = 0; i < 4; ++i)
      af[i] = *(const half8*)(&As[(wm + i * 16 + l15) * 72 + kk + l4 * 8]);
#pragma unroll
    for (int j = 0; j < 6; ++j)
      bf[j] = *(const half8*)(&Bs[(wn + j * 16 + l15) * 72 + kk + l4 * 8]);
#pragma unroll
    for (int i = 0; i < 4; ++i)
#pragma unroll
      for (int j = 0; j < 6; ++j)
        acc[i][j] = __builtin_amdgcn_mfma_f32_16x16x32_f16(
            af[i], bf[j], acc[i][j], 0, 0, 0);
  }
#pragma unroll
  for (int j = 0; j < 6; ++j) {
    int n = wn + j * 16 + l15;           // 0..191
    int which = n >> 6, e = n & 63;
    const float* bias = which == 0 ? bq : which == 1 ? bk : bv;
    float bval = bias[h * 64 + e];
#pragma unroll
    for (int i = 0; i < 4; ++i) {
#pragma unroll
      for (int r = 0; r < 4; ++r) {
        int tok = bm + wm + i * 16 + l4 * 4 + r;   // token index
        if (tok < VB * VS) {
          int b = tok / VS, s = tok - b * VS;
          size_t bh = (size_t)b * VNH + h;
          unsigned short val = f2h(acc[i][j][r] + bval);
          if (which == 0)      qh[(bh * VS + s) * 64 + e] = val;
          else if (which == 1) kh[(bh * VS + s) * 64 + e] = val;
          else                 vt[(bh * 64 + e) * 208 + s] = val;
        }
      }
    }
  }
}

// zero vt pad columns 197..207 (aliased scratch may hold NaN-pattern fp16)
__global__ __launch_bounds__(256) void vt_ztail(unsigned short* __restrict__ vt) {
  int i = blockIdx.x * 256 + threadIdx.x;   // < 384*64*11
  int c = i % 11;
  int rd = i / 11;                           // bh*64 + d
  vt[(size_t)rd * 208 + 197 + c] = 0;
}

// ---------------------------------------------------------------- attention
// MFMA flash-ish: grid (bh, qtile). 4 waves x 16 q-rows each.
#define PSTR 212
__global__ __launch_bounds__(256) void attn_mfma(
    const unsigned short* __restrict__ qh,   // [384*197][64] fp16
    const unsigned short* __restrict__ kh,   // [384*197][64] fp16
    const unsigned short* __restrict__ vt,   // [384*64][208] fp16
    float* __restrict__ out) {
  int bh = blockIdx.x;                 // b*12 + h
  int qt = blockIdx.y;                 // 0..3
  int t = threadIdx.x;
  int w = t >> 6, lane = t & 63;
  int l15 = lane & 15, l4 = lane >> 4;
  __shared__ unsigned short Pl[4][16 * PSTR];

  int qrow = qt * 64 + w * 16 + l15;
  const unsigned short* qbase = qh + ((size_t)bh * VS) * 64;
  const unsigned short* kbase = kh + ((size_t)bh * VS) * 64;
  half8 qf0 = *(const half8*)(qbase + (size_t)qrow * 64 + l4 * 8);
  half8 qf1 = *(const half8*)(qbase + (size_t)qrow * 64 + 32 + l4 * 8);

  f32x4 S[13];
#pragma unroll
  for (int j = 0; j < 13; ++j) {
    half8 b0 = *(const half8*)(kbase + (size_t)(j * 16 + l15) * 64 + l4 * 8);
    half8 b1 = *(const half8*)(kbase + (size_t)(j * 16 + l15) * 64 + 32 + l4 * 8);
    f32x4 c = {};
    c = __builtin_amdgcn_mfma_f32_16x16x32_f16(qf0, b0, c, 0, 0, 0);
    c = __builtin_amdgcn_mfma_f32_16x16x32_f16(qf1, b1, c, 0, 0, 0);
    S[j] = c;
  }
  float m4[4] = {-3.0e38f, -3.0e38f, -3.0e38f, -3.0e38f};
#pragma unroll
  for (int j = 0; j < 13; ++j) {
#pragma unroll
    for (int r = 0; r < 4; ++r) {
      float s = S[j][r] * 0.125f;
      if (j == 12 && l15 > 4) s = -3.0e38f;
      S[j][r] = s;
      m4[r] = fmaxf(m4[r], s);
    }
  }
#pragma unroll
  for (int off = 1; off < 16; off <<= 1) {
#pragma unroll
    for (int r = 0; r < 4; ++r) m4[r] = fmaxf(m4[r], __shfl_xor(m4[r], off));
  }
  float ls[4] = {0.f, 0.f, 0.f, 0.f};
#pragma unroll
  for (int j = 0; j < 13; ++j) {
#pragma unroll
    for (int r = 0; r < 4; ++r) {
      float p = __expf(S[j][r] - m4[r]);
      S[j][r] = p;
      ls[r] += p;
    }
  }
#pragma unroll
  for (int off = 1; off < 16; off <<= 1) {
#pragma unroll
    for (int r = 0; r < 4; ++r) ls[r] += __shfl_xor(ls[r], off);
  }
  unsigned short* Pw = &Pl[w][0];
#pragma unroll
  for (int j = 0; j < 13; ++j) {
#pragma unroll
    for (int r = 0; r < 4; ++r)
      Pw[(l4 * 4 + r) * PSTR + j * 16 + l15] = f2h(S[j][r]);
  }
  const unsigned short* vbase = vt + (size_t)bh * 64 * 208;
  f32x4 O[4] = {};
#pragma unroll
  for (int jk = 0; jk < 13; ++jk) {
    half4 a = *(const half4*)(Pw + l15 * PSTR + jk * 16 + l4 * 4);
#pragma unroll
    for (int jn = 0; jn < 4; ++jn) {
      half4 b = *(const half4*)(vbase + (size_t)(jn * 16 + l15) * 208 + jk * 16 + l4 * 4);
      O[jn] = __builtin_amdgcn_mfma_f32_16x16x16f16(a, b, O[jn], 0, 0, 0);
    }
  }
  int b = bh / VNH, h = bh - (bh / VNH) * VNH;
  float linv[4];
#pragma unroll
  for (int r = 0; r < 4; ++r) linv[r] = 1.0f / ls[r];
#pragma unroll
  for (int r = 0; r < 4; ++r) {
    int qr = qt * 64 + w * 16 + l4 * 4 + r;
    if (qr < VS) {
      float* op = out + ((size_t)b * VS + qr) * VD + h * VDH;
#pragma unroll
      for (int jn = 0; jn < 4; ++jn)
        op[jn * 16 + l15] += O[jn][r] * linv[r];
    }
  }
}

// ---------------------------------------------------------------- MFMA GEMM (128x128, 2-phase; kept for embed)
// C[M,N] = A[M,K](fp16) @ Bt[N,K](fp16)^T + bias
// EPI: 0 = store fp32 (REMAP), 1 = gelu -> fp16, 2 = += fp32, 3 = raw fp32
template <int EPI, int REMAP>
__global__ __launch_bounds__(256) void gemm_h(
    const unsigned short* __restrict__ A,
    const unsigned short* __restrict__ Bt,
    const float* __restrict__ bias, float* __restrict__ C,
    int M, int N, int K, int KS) {
  __shared__ unsigned short As[128 * 64];
  __shared__ unsigned short Bs[128 * 64];
  int t = threadIdx.x;
  int bm = blockIdx.y * 128, bn = blockIdx.x * 128;
  int lane = t & 63, w = t >> 6;
  int wm = (w & 1) * 64, wn = (w >> 1) * 64;
  int l15 = lane & 15, l4 = lane >> 4;
  int lrow = lane >> 3, lcol = (lane & 7) * 8;
  f32x4 acc[4][4] = {};
  int kbeg = blockIdx.z * KS;
  if (EPI == 3) C += (size_t)blockIdx.z * M * N;
  for (int k0 = kbeg; k0 < kbeg + KS; k0 += 64) {
#pragma unroll
    for (int p = 0; p < 4; ++p) {
      int r0 = w * 32 + p * 8;
      int ga = bm + r0;
      if (ga > M - 8) ga = M - 8;     // clamp; LDS row untouched
      gload_lds16(A + (size_t)(ga + lrow) * K + k0 + lcol, &As[r0 * 64]);
      gload_lds16(Bt + (size_t)(bn + r0 + lrow) * K + k0 + lcol, &Bs[r0 * 64]);
    }
    __syncthreads();
#pragma unroll
    for (int kk = 0; kk < 64; kk += 32) {
      half8 af[4], bf[4];
#pragma unroll
      for (int i = 0; i < 4; ++i)
        af[i] = *(const half8*)(&As[(wm + i * 16 + l15) * 64 + kk + l4 * 8]);
#pragma unroll
      for (int j = 0; j < 4; ++j)
        bf[j] = *(const half8*)(&Bs[(wn + j * 16 + l15) * 64 + kk + l4 * 8]);
#pragma unroll
      for (int i = 0; i < 4; ++i)
#pragma unroll
        for (int j = 0; j < 4; ++j)
          acc[i][j] = __builtin_amdgcn_mfma_f32_16x16x32_f16(
              af[i], bf[j], acc[i][j], 0, 0, 0);
    }
    __syncthreads();
  }
#pragma unroll
  for (int i = 0; i < 4; ++i) {
#pragma unroll
    for (int j = 0; j < 4; ++j) {
#pragma unroll
      for (int r = 0; r < 4; ++r) {
        int row = bm + wm + i * 16 + l4 * 4 + r;
        int col = bn + wn + j * 16 + l15;
        if (row < M) {
          if (EPI == 3) {
            C[(size_t)row * N + col] = acc[i][j][r];
          } else {
            float val = acc[i][j][r] + bias[col];
            if (EPI == 0) {
              int crow = REMAP ? (row + row / 196 + 1) : row;
              C[(size_t)crow * N + col] = val;
            } else if (EPI == 1) {
              val = 0.5f * val * (1.0f + erff(val * 0.70710678118654752440f));
              ((unsigned short*)C)[(size_t)row * N + col] = f2h(val);
            } else {
              C[(size_t)row * N + col] += val;
            }
          }
        }
      }
    }
  }
}

// ---------------------------------------------------------------- 256x256 8-phase GEMM
// C[M,N] = A[M,K](fp16) @ Bt[N,K](fp16)^T   (template per guide §5 / m201)
// EPI: 1 = bias+gelu -> fp16 store, 3 = raw fp32 partial (split-K via blockIdx.z)
// BM=BN=256, BK=64, 512 thr = 8 waves (2M x 4N), per-wave out 128x64.
// LDS 128 KB: 2 slots x (A 32KB + B 32KB), subtiled [r/16][c/32][16][32] fp16
// (1024B subtiles) with st_16x32 XOR swizzle: byte ^= ((byte>>9)&1)<<5.
// Staging: global_load_lds (linear dest) + inverse-swizzled per-lane SOURCE;
// reads apply the same XOR (both-sides rule). One half-tile (2 gloads/wave)
// staged per phase, into regions proven dead:
//   slot B dies after its 2nd compute phase, slot A after its 3rd.
// Counted s_waitcnt vmcnt(4) at phases 4 and 8 only (never 0 in the loop).
#define GSB0() __builtin_amdgcn_sched_barrier(0)

template <int EPI>
__global__ __launch_bounds__(512, 2) void gemm256(
    const unsigned short* __restrict__ A,
    const unsigned short* __restrict__ Bt,
    const float* __restrict__ bias, float* __restrict__ C,
    int M, int N, int K, int KS) {
  __shared__ uint4 lds4[8192];            // 128 KB
  char* ldsb = (char*)lds4;
  int t = threadIdx.x;
  int w = t >> 6, lane = t & 63;
  int wm = w >> 2, wn = w & 3;            // 2 x 4 wave grid
  int l15 = lane & 15, l4 = lane >> 4;
  int bm = blockIdx.y * 256, bn = blockIdx.x * 256;
  int kbeg = blockIdx.z * KS;
  int kmax = kbeg + KS - 64;              // stage-k clamp (last-iter over-stage is dead-region safe)
  if (EPI == 3) C += (size_t)blockIdx.z * M * N;
  // per-lane swizzled read offset within a 1KB subtile: rows via l15, 16B col chunk via l4
  int laneoff = ((l15 << 6) | (l4 << 4)) ^ ((l15 & 8) << 2);
  // per-lane staging source decomposition: physical chunk lane -> logical chunk
  int cl = lane ^ ((lane & 32) >> 4);
  int rin = cl >> 2, c8 = (cl & 3) << 3;

  f32x4 acc[8][4] = {};
  half8 af[4][2], bf0[2][2], bf1[2][2];

// stage one half-tile (16 subtiles); wave w takes subtiles half*16 + q*8 + w
#define STAGE_A(sl, half, kt)                                                  \
  {                                                                            \
    int kc = (kt); if (kc > kmax) kc = kmax;                                   \
    _Pragma("unroll") for (int q = 0; q < 2; ++q) {                            \
      int s = (half) * 16 + q * 8 + w;                                         \
      int grow = bm + (s >> 1) * 16 + rin;                                     \
      if (grow >= M) grow = M - 1;                                             \
      gload_lds16(A + (size_t)grow * K + kc + ((s & 1) << 5) + c8,             \
                  ldsb + (sl) * 65536 + s * 1024);                             \
    }                                                                          \
  }
#define STAGE_B(sl, half, kt)                                                  \
  {                                                                            \
    int kc = (kt); if (kc > kmax) kc = kmax;                                   \
    _Pragma("unroll") for (int q = 0; q < 2; ++q) {                            \
      int s = (half) * 16 + q * 8 + w;                                         \
      gload_lds16(Bt + (size_t)(bn + (s >> 1) * 16 + rin) * K + kc +           \
                      ((s & 1) << 5) + c8,                                     \
                  ldsb + (sl) * 65536 + 32768 + s * 1024);                     \
    }                                                                          \
  }
#define PH_LOADA(sl, mq)                                                       \
  {                                                                            \
    _Pragma("unroll") for (int mf = 0; mf < 4; ++mf) {                         \
      int sub = (wm * 8 + (mq) * 4 + mf) * 2048;                               \
      af[mf][0] = *(const half8*)(ldsb + (sl) * 65536 + sub + laneoff);        \
      af[mf][1] = *(const half8*)(ldsb + (sl) * 65536 + sub + 1024 + laneoff); \
    }                                                                          \
  }
#define PH_LOADB(sl, nq, BF)                                                   \
  {                                                                            \
    _Pragma("unroll") for (int nf = 0; nf < 2; ++nf) {                         \
      int sub = (wn * 4 + (nq) * 2 + nf) * 2048;                               \
      BF[nf][0] = *(const half8*)(ldsb + (sl) * 65536 + 32768 + sub + laneoff);\
      BF[nf][1] = *(const half8*)(ldsb + (sl) * 65536 + 32768 + sub + 1024 + laneoff); \
    }                                                                          \
  }
#define PH_MMA(mq, nq, BF)                                                     \
  __builtin_amdgcn_s_setprio(1);                                               \
  _Pragma("unroll") for (int mf = 0; mf < 4; ++mf)                             \
  _Pragma("unroll") for (int nf = 0; nf < 2; ++nf) {                           \
    acc[(mq)*4+mf][(nq)*2+nf] = __builtin_amdgcn_mfma_f32_16x16x32_f16(        \
        af[mf][0], BF[nf][0], acc[(mq)*4+mf][(nq)*2+nf], 0, 0, 0);             \
    acc[(mq)*4+mf][(nq)*2+nf] = __builtin_amdgcn_mfma_f32_16x16x32_f16(        \
        af[mf][1], BF[nf][1], acc[(mq)*4+mf][(nq)*2+nf], 0, 0, 0);             \
  }                                                                            \
  __builtin_amdgcn_s_setprio(0);
#define GBAR() __builtin_amdgcn_s_barrier()
#define WAIT_LGKM0() { asm volatile("s_waitcnt lgkmcnt(0)" ::: "memory"); GSB0(); }
#define WAIT_VM4()   { asm volatile("s_waitcnt vmcnt(4)"   ::: "memory"); GSB0(); }

  // prologue: tile0 (slot0) fully + tile1's B (slot1); oldest 8 = tile0
  STAGE_A(0, 0, kbeg); STAGE_A(0, 1, kbeg);
  STAGE_B(0, 0, kbeg); STAGE_B(0, 1, kbeg);
  STAGE_B(1, 0, kbeg + 64); STAGE_B(1, 1, kbeg + 64);
  WAIT_VM4();            // 12 issued -> retire 8 oldest = tile0 landed
  GBAR(); GSB0();

  int NITER = KS >> 7;   // KS multiple of 128
  for (int j = 0; j < NITER; ++j) {
    int k0 = kbeg + j * 128;
    // ---- p1: slot0 (mq0,nq0); stage slot1.A h0 (tile k0+64)
    PH_LOADA(0, 0); PH_LOADB(0, 0, bf0);
    STAGE_A(1, 0, k0 + 64);
    GBAR(); WAIT_LGKM0();
    PH_MMA(0, 0, bf0);
    GBAR(); GSB0();
    // ---- p2: (mq0,nq1); stage slot1.A h1
    PH_LOADB(0, 1, bf1);
    STAGE_A(1, 1, k0 + 64);
    GBAR(); WAIT_LGKM0();
    PH_MMA(0, 1, bf1);
    GBAR(); GSB0();
    // ---- p3: (mq1,nq0); slot0.B dead after p2 -> stage slot0.B h0 (k0+128)
    PH_LOADA(0, 1);
    STAGE_B(0, 0, k0 + 128);
    GBAR(); WAIT_LGKM0();
    PH_MMA(1, 0, bf0);
    GBAR(); GSB0();
    // ---- p4: (mq1,nq1); stage slot0.B h1; counted vmcnt -> slot1 tile landed
    STAGE_B(0, 1, k0 + 128);
    GBAR(); WAIT_LGKM0();
    PH_MMA(1, 1, bf1);
    WAIT_VM4();
    GBAR(); GSB0();
    // ---- p5: slot1 (mq0,nq0); slot0.A dead after p3 -> stage slot0.A h0
    PH_LOADA(1, 0); PH_LOADB(1, 0, bf0);
    STAGE_A(0, 0, k0 + 128);
    GBAR(); WAIT_LGKM0();
    PH_MMA(0, 0, bf0);
    GBAR(); GSB0();
    // ---- p6: (mq0,nq1); stage slot0.A h1
    PH_LOADB(1, 1, bf1);
    STAGE_A(0, 1, k0 + 128);
    GBAR(); WAIT_LGKM0();
    PH_MMA(0, 1, bf1);
    GBAR(); GSB0();
    // ---- p7: (mq1,nq0); slot1.B dead after p6 -> stage slot1.B h0 (k0+192)
    PH_LOADA(1, 1);
    STAGE_B(1, 0, k0 + 192);
    GBAR(); WAIT_LGKM0();
    PH_MMA(1, 0, bf0);
    GBAR(); GSB0();
    // ---- p8: (mq1,nq1); stage slot1.B h1; counted vmcnt -> slot0 tile landed
    STAGE_B(1, 1, k0 + 192);
    GBAR(); WAIT_LGKM0();
    PH_MMA(1, 1, bf1);
    WAIT_VM4();
    GBAR(); GSB0();
  }

  // epilogue
#pragma unroll
  for (int m = 0; m < 8; ++m) {
#pragma unroll
    for (int n = 0; n < 4; ++n) {
      int col = bn + wn * 64 + n * 16 + l15;
#pragma unroll
      for (int r = 0; r < 4; ++r) {
        int row = bm + wm * 128 + m * 16 + l4 * 4 + r;
        if (row < M) {
          if (EPI == 1) {
            float val = acc[m][n][r] + bias[col];
            val = 0.5f * val * (1.0f + erff(val * 0.70710678118654752440f));
            ((unsigned short*)C)[(size_t)row * N + col] = f2h(val);
          } else {
            C[(size_t)row * N + col] = acc[m][n][r];
          }
        }
      }
    }
  }
#undef STAGE_A
#undef STAGE_B
#undef PH_LOADA
#undef PH_LOADB
#undef PH_MMA
#undef GBAR
#undef WAIT_LGKM0
#undef WAIT_VM4
}

// out += p0 + p1 + bias  (split-K reduce for MLP2)
__global__ __launch_bounds__(256) void mlp2_reduce(
    const float* __restrict__ p0, const float* __restrict__ p1,
    const float* __restrict__ bias, float* __restrict__ out) {
  size_t idx = ((size_t)blockIdx.x * 256 + threadIdx.x) * 4;  // < 6304*768
  int col = (int)(idx % VD);
  float4 a = *(const float4*)(p0 + idx);
  float4 b = *(const float4*)(p1 + idx);
  float4 bi = *(const float4*)(bias + col);
  float4 o = *(const float4*)(out + idx);
  o.x += a.x + b.x + bi.x;
  o.y += a.y + b.y + bi.y;
  o.z += a.z + b.z + bi.z;
  o.w += a.w + b.w + bi.w;
  *(float4*)(out + idx) = o;
}

// ---------------------------------------------------------------- classifier
__global__ __launch_bounds__(256) void cls_logits(
    const float* __restrict__ out_act, const float* __restrict__ Wc,
    const float* __restrict__ bc, float* __restrict__ lbuf) {
  int b = blockIdx.y;
  int n0 = blockIdx.x * 250;
  int t = threadIdx.x;
  __shared__ float xs[768];
  const float* xr = out_act + (size_t)b * VS * VD;  // cls token row
  xs[t] = xr[t]; xs[t + 256] = xr[t + 256]; xs[t + 512] = xr[t + 512];
  __syncthreads();
  if (t < 250) {
    int col = n0 + t;
    float acc = bc[col];
#pragma unroll 4
    for (int d = 0; d < VD; ++d) acc += xs[d] * Wc[(size_t)d * VOUT + col];
    lbuf[(size_t)b * VOUT + col] = acc;
  }
}

__global__ __launch_bounds__(256) void cls_softmax(
    const float* __restrict__ lbuf, float* __restrict__ y) {
  int b = blockIdx.x;
  int t = threadIdx.x;
  __shared__ float logit[VOUT];
  __shared__ float red[10];
  for (int j = t; j < VOUT; j += 256) logit[j] = lbuf[(size_t)b * VOUT + j];
  __syncthreads();
  float m = -1e30f;
  for (int j = t; j < VOUT; j += 256) m = fmaxf(m, logit[j]);
#pragma unroll
  for (int off = 32; off; off >>= 1) m = fmaxf(m, __shfl_down(m, off));
  if ((t & 63) == 0) red[t >> 6] = m;
  __syncthreads();
  if (t == 0) red[8] = fmaxf(fmaxf(red[0], red[1]), fmaxf(red[2], red[3]));
  __syncthreads();
  float M = red[8];
  float s = 0.f;
  for (int j = t; j < VOUT; j += 256) {
    float e = expf(logit[j] - M);
    logit[j] = e;
    s += e;
  }
#pragma unroll
  for (int off = 32; off; off >>= 1) s += __shfl_down(s, off);
  if ((t & 63) == 0) red[4 + (t >> 6)] = s;
  __syncthreads();
  if (t == 0) red[9] = red[4] + red[5] + red[6] + red[7];
  __syncthreads();
  float inv = 1.0f / red[9];
  for (int j = t; j < VOUT; j += 256) y[(size_t)b * VOUT + j] = logit[j] * inv;
}

// ---------------------------------------------------------------- launch
extern "C" void kernel_launch(void* const* d_in, const int* in_sizes, int n_in,
                              void* d_out, int out_size, void* d_ws, size_t ws_size,
                              hipStream_t stream) {
  const float* x      = (const float*)d_in[0];
  const float* cls    = (const float*)d_in[1];
  const float* pos    = (const float*)d_in[2];
  const float* Wmap   = (const float*)d_in[3];
  const float* bmap   = (const float*)d_in[4];
  const float* ln1_g  = (const float*)d_in[5];
  const float* ln1_b  = (const float*)d_in[6];
  const float* Wq     = (const float*)d_in[7];
  const float* bq     = (const float*)d_in[8];
  const float* Wk     = (const float*)d_in[9];
  const float* bk     = (const float*)d_in[10];
  const float* Wv     = (const float*)d_in[11];
  const float* bv     = (const float*)d_in[12];
  const float* ln2_g  = (const float*)d_in[13];
  const float* ln2_b  = (const float*)d_in[14];
  const float* W1     = (const float*)d_in[15];
  const float* b1     = (const float*)d_in[16];
  const float* W2     = (const float*)d_in[17];
  const float* b2     = (const float*)d_in[18];
  const float* Wc     = (const float*)d_in[19];
  const float* bc     = (const float*)d_in[20];
  float* yout = (float*)d_out;

  const size_t nBS  = (size_t)VB * VS;          // 6304
  const size_t nBSD = nBS * VD;                 // 4,841,472
  const size_t nQK  = (size_t)VB * VNH * VS * 64;   // 4,841,472
  char* base = (char*)d_ws;
  size_t off = 0;
  float* out_act = (float*)(base + off);      off += nBSD * 4;
  unsigned short* xnb = (unsigned short*)(base + off); off += nBSD * 2;
  unsigned short* qhb = (unsigned short*)(base + off); off += nQK * 2 + 65536;
  unsigned short* khb = (unsigned short*)(base + off); off += nQK * 2 + 65536;
  unsigned short* vtb = (unsigned short*)(base + off); off += (size_t)VB * VNH * 64 * 208 * 2;
  unsigned short* hbuf = (unsigned short*)(base + off); off += nBS * VMLP * 2;
  unsigned short* wmapT = (unsigned short*)(base + off); off += (size_t)VD * VD * 2;
  unsigned short* w1T = (unsigned short*)(base + off);   off += (size_t)VL * VMLP * VD * 2;
  unsigned short* w2T = (unsigned short*)(base + off);   off += (size_t)VL * VD * VMLP * 2;
  unsigned short* wqkv = (unsigned short*)(base + off);  off += (size_t)VL * VNH * 192 * 64 * 2;
  // split-K partials alias the (dead-during-MLP2) xnb/qhb/khb/vtb region
  float* part = (float*)xnb;                 // 2 * nBSD floats fit in 39.4 MB
  float* lbuf = (float*)qhb;                 // classifier logits (32x1000)

  // weight transposes / packs (fp32 -> fp16)
  transpose_kernel<<<dim3(12, 12, 1), 256, 0, stream>>>(Wmap, wmapT, VD, VD);
  transpose_kernel<<<dim3(48, 12, VL), 256, 0, stream>>>(W1, w1T, VD, VMLP);
  transpose_kernel<<<dim3(12, 48, VL), 256, 0, stream>>>(W2, w2T, VMLP, VD);
  pack_qkv_kernel<<<(VL * VNH * 192 * 64) / 256, 256, 0, stream>>>(Wq, Wk, Wv, wqkv);

  // patchify (fp16 patches into hbuf)
  patchify_kernel<<<VB * VNPAT, 256, 0, stream>>>(x, hbuf);
  // embed GEMM: out rows [b*197 + 1 + p]
  gemm_h<0, 1><<<dim3(6, 49), 256, 0, stream>>>(
      hbuf, wmapT, bmap, out_act, VB * VNPAT, VD, VD, VD);
  // cls token + positional embedding
  addpos_kernel<<<(int)nBS, 256, 0, stream>>>(cls, pos, out_act);

  for (int l = 0; l < VL; l++) {
    ln_kernel<<<(int)nBS, 256, 0, stream>>>(out_act, xnb,
                                            ln1_g + (size_t)l * VD,
                                            ln1_b + (size_t)l * VD);
    qkv_gemm<<<dim3(50, VNH), 256, 0, stream>>>(
        xnb, wqkv + (size_t)l * VNH * 192 * 64,
        bq + (size_t)l * VNH * VDH, bk + (size_t)l * VNH * VDH,
        bv + (size_t)l * VNH * VDH, qhb, khb, vtb);
    vt_ztail<<<(VB * VNH * 64 * 11) / 256, 256, 0, stream>>>(vtb);
    attn_mfma<<<dim3(VB * VNH, 4), 256, 0, stream>>>(qhb, khb, vtb, out_act);
    ln_kernel<<<(int)nBS, 256, 0, stream>>>(out_act, xnb,
                                            ln2_g + (size_t)l * VD,
                                            ln2_b + (size_t)l * VD);
    // MLP1: h = gelu(xn @ W1 + b1) -> fp16 hbuf  (256^2 8-phase)
    gemm256<1><<<dim3(VMLP / 256, 25, 1), 512, 0, stream>>>(
        xnb, w1T + (size_t)l * VMLP * VD, b1 + (size_t)l * VMLP,
        (float*)hbuf, (int)nBS, VMLP, VD, VD);
    // MLP2 split-K=2: partials then reduce (out += p0+p1+b2)  (256^2 8-phase)
    gemm256<3><<<dim3(VD / 256, 25, 2), 512, 0, stream>>>(
        hbuf, w2T + (size_t)l * VD * VMLP, nullptr,
        part, (int)nBS, VD, VMLP, VMLP / 2);
    mlp2_reduce<<<(int)(nBSD / 1024), 256, 0, stream>>>(
        part, part + nBSD, b2 + (size_t)l * VD, out_act);
  }
  cls_logits<<<dim3(4, VB), 256, 0, stream>>>(out_act, Wc, bc, lbuf);
  cls_softmax<<<VB, 256, 0, stream>>>(lbuf, yout);
}